// Round 9
// baseline (285.727 us; speedup 1.0000x reference)
//
#include <hip/hip_runtime.h>

typedef unsigned short u16;
typedef unsigned short u16x8 __attribute__((ext_vector_type(8)));
typedef short s16x8 __attribute__((ext_vector_type(8)));
typedef float f32x4 __attribute__((ext_vector_type(4)));
typedef float f32x16 __attribute__((ext_vector_type(16)));
typedef unsigned u32x4 __attribute__((ext_vector_type(4)));

__device__ __forceinline__ u16 f2b(float f){
  unsigned u = __builtin_bit_cast(unsigned, f);
  u += 0x7fffu + ((u >> 16) & 1u);
  return (u16)(u >> 16);
}
__device__ __forceinline__ float b2f(u16 v){
  unsigned u = ((unsigned)v) << 16;
  return __builtin_bit_cast(float, u);
}

#define MFMA16(c, a, b) (c) = __builtin_amdgcn_mfma_f32_16x16x32_bf16((a), (b), (c), 0, 0, 0)
#define MFMA32(c, a, b) (c) = __builtin_amdgcn_mfma_f32_32x32x16_bf16((a), (b), (c), 0, 0, 0)

__device__ __forceinline__ void gl16(const u16* g, char* l){
  __builtin_amdgcn_global_load_lds((const __attribute__((address_space(1))) void*)g,
                                   (__attribute__((address_space(3))) void*)l, 16, 0, 0);
}

// ---------------- cast hidden_states f32 -> bf16 ----------------
__global__ void k_cast(const float* __restrict__ src, u16* __restrict__ dst, int n8){
  int i = blockIdx.x * blockDim.x + threadIdx.x;
  if (i >= n8) return;
  const float4* s = (const float4*)(src + (size_t)i * 8);
  float4 a = s[0], b = s[1];
  u16x8 o;
  o[0]=f2b(a.x); o[1]=f2b(a.y); o[2]=f2b(a.z); o[3]=f2b(a.w);
  o[4]=f2b(b.x); o[5]=f2b(b.y); o[6]=f2b(b.z); o[7]=f2b(b.w);
  *(u16x8*)(dst + (size_t)i * 8) = o;
}

// ------- transpose+cast: src (K x N f32) -> dst (N x K bf16) -------
__global__ void k_transpose(const float* __restrict__ src, u16* __restrict__ dst, int K, int N){
  __shared__ float t[32][33];
  int n0 = blockIdx.x * 32, k0 = blockIdx.y * 32;
  int c = threadIdx.x & 31, r4 = threadIdx.x >> 5;
  #pragma unroll
  for (int p = 0; p < 4; ++p){
    int r = r4 + p * 8;
    t[r][c] = src[(size_t)(k0 + r) * N + n0 + c];
  }
  __syncthreads();
  #pragma unroll
  for (int p = 0; p < 4; ++p){
    int r = r4 + p * 8;
    dst[(size_t)(n0 + r) * K + k0 + c] = f2b(t[c][r]);
  }
}

// ---------------- 8-phase GEMM: C = A(MxK) * BT(NxK)^T ----------------
template<int NREP, bool OBF>
__global__ __launch_bounds__(512, 1) void k_gemm8(const u16* __restrict__ A, const u16* __restrict__ BT,
                                                  void* __restrict__ Cv, int M, int N, int K){
  constexpr int NH = NREP / 2;
  constexpr int BROWS = NREP * 32;
  constexpr int BLOADS = NREP / 2;
  constexpr int TOT = 4 + 2 * BLOADS;
  __shared__ __align__(16) u16 sA[2][2][128 * 64];
  __shared__ __align__(16) u16 sB[2][2][BROWS * 64];
  const int tid = threadIdx.x;
  const int lane = tid & 63, w = tid >> 6;
  const int l15 = lane & 15, l4 = lane >> 4;
  const int sx = l15 & 7;
  const int wr = w >> 2, wc = w & 3;
  const int m0 = blockIdx.y * 256, n0 = blockIdx.x * (NREP * 64);
  const int nk = K >> 6;

  f32x4 acc[8][NREP];
  #pragma unroll
  for (int mi = 0; mi < 8; ++mi)
    #pragma unroll
    for (int ni = 0; ni < NREP; ++ni) acc[mi][ni] = (f32x4){0.f, 0.f, 0.f, 0.f};

  auto stageA = [&](int d, int half, int k0){
    #pragma unroll
    for (int j = 0; j < 2; ++j){
      const int q = j * 512 + tid;
      const int r = q >> 3, cc = q & 7;
      gl16(A + (size_t)(m0 + half * 128 + r) * K + k0 + ((cc ^ (r & 7)) << 3),
           (char*)&sA[d][half][0] + j * 8192 + (tid >> 6) * 1024);
    }
  };
  auto stageB = [&](int d, int half, int k0){
    #pragma unroll
    for (int j = 0; j < BLOADS; ++j){
      const int q = j * 512 + tid;
      const int r = q >> 3, cc = q & 7;
      gl16(BT + (size_t)(n0 + half * BROWS + r) * K + k0 + ((cc ^ (r & 7)) << 3),
           (char*)&sB[d][half][0] + j * 8192 + (tid >> 6) * 1024);
    }
  };

  stageA(0, 0, 0); stageA(0, 1, 0); stageB(0, 0, 0); stageB(0, 1, 0);
  stageA(1, 0, 64); stageA(1, 1, 64); stageB(1, 0, 64); stageB(1, 1, 64);
  if constexpr (TOT == 8) asm volatile("s_waitcnt vmcnt(8)" ::: "memory");
  else                    asm volatile("s_waitcnt vmcnt(6)" ::: "memory");
  __builtin_amdgcn_s_barrier();

  const int halfB = wc >> 1;
  const int rb0 = (wc & 1) * (NREP * 16);

  for (int kt = 0; kt < nk; ++kt){
    const int d = kt & 1;
    const bool pre = (kt + 2) < nk;
    const int k0n = (kt + 2) << 6;
    const char* hA = (const char*)&sA[d][wr][0];
    const char* hB = (const char*)&sB[d][halfB][0];
    s16x8 aa[4][2], bb0[NH][2], bb1[NH][2];

    #pragma unroll
    for (int mi = 0; mi < 4; ++mi)
      #pragma unroll
      for (int kk = 0; kk < 2; ++kk)
        aa[mi][kk] = *(const s16x8*)(hA + (mi * 16 + l15) * 128 + (((kk * 4 + l4) ^ sx) << 4));
    #pragma unroll
    for (int ni = 0; ni < NH; ++ni)
      #pragma unroll
      for (int kk = 0; kk < 2; ++kk)
        bb0[ni][kk] = *(const s16x8*)(hB + (rb0 + ni * 16 + l15) * 128 + (((kk * 4 + l4) ^ sx) << 4));
    __builtin_amdgcn_s_setprio(1);
    #pragma unroll
    for (int mi = 0; mi < 4; ++mi)
      #pragma unroll
      for (int ni = 0; ni < NH; ++ni)
        #pragma unroll
        for (int kk = 0; kk < 2; ++kk)
          MFMA16(acc[mi][ni], aa[mi][kk], bb0[ni][kk]);
    __builtin_amdgcn_s_setprio(0);

    #pragma unroll
    for (int ni = 0; ni < NH; ++ni)
      #pragma unroll
      for (int kk = 0; kk < 2; ++kk)
        bb1[ni][kk] = *(const s16x8*)(hB + (rb0 + (NH + ni) * 16 + l15) * 128 + (((kk * 4 + l4) ^ sx) << 4));
    __builtin_amdgcn_s_setprio(1);
    #pragma unroll
    for (int mi = 0; mi < 4; ++mi)
      #pragma unroll
      for (int ni = 0; ni < NH; ++ni)
        #pragma unroll
        for (int kk = 0; kk < 2; ++kk)
          MFMA16(acc[mi][NH + ni], aa[mi][kk], bb1[ni][kk]);
    __builtin_amdgcn_s_setprio(0);
    __builtin_amdgcn_s_barrier();

    #pragma unroll
    for (int mi = 0; mi < 4; ++mi)
      #pragma unroll
      for (int kk = 0; kk < 2; ++kk)
        aa[mi][kk] = *(const s16x8*)(hA + ((mi + 4) * 16 + l15) * 128 + (((kk * 4 + l4) ^ sx) << 4));
    if (pre){ stageB(d, 0, k0n); stageB(d, 1, k0n); }
    __builtin_amdgcn_s_setprio(1);
    #pragma unroll
    for (int mi = 0; mi < 4; ++mi)
      #pragma unroll
      for (int ni = 0; ni < NH; ++ni)
        #pragma unroll
        for (int kk = 0; kk < 2; ++kk)
          MFMA16(acc[mi + 4][ni], aa[mi][kk], bb0[ni][kk]);
    __builtin_amdgcn_s_setprio(0);
    __builtin_amdgcn_s_barrier();

    if (pre){ stageA(d, 0, k0n); stageA(d, 1, k0n); }
    __builtin_amdgcn_s_setprio(1);
    #pragma unroll
    for (int mi = 0; mi < 4; ++mi)
      #pragma unroll
      for (int ni = 0; ni < NH; ++ni)
        #pragma unroll
        for (int kk = 0; kk < 2; ++kk)
          MFMA16(acc[mi + 4][NH + ni], aa[mi][kk], bb1[ni][kk]);
    __builtin_amdgcn_s_setprio(0);
    if (kt + 1 < nk){
      if (pre){
        if constexpr (TOT == 8) asm volatile("s_waitcnt vmcnt(8)" ::: "memory");
        else                    asm volatile("s_waitcnt vmcnt(6)" ::: "memory");
      } else {
        asm volatile("s_waitcnt vmcnt(0)" ::: "memory");
      }
      __builtin_amdgcn_s_barrier();
    }
  }

  #pragma unroll
  for (int mi = 0; mi < 8; ++mi)
    #pragma unroll
    for (int ni = 0; ni < NREP; ++ni)
      #pragma unroll
      for (int i = 0; i < 4; ++i){
        const int row = m0 + wr * 128 + mi * 16 + l4 * 4 + i;
        const int col = n0 + wc * (NREP * 16) + ni * 16 + l15;
        if constexpr (OBF) ((u16*)Cv)[(size_t)row * N + col] = f2b(acc[mi][ni][i]);
        else               ((float*)Cv)[(size_t)row * N + col] = acc[mi][ni][i];
      }
}

// ---------------- fused RMSNorm + RoPE + split/cast (bf16 input) ----------------
// Q outputs pre-scaled by HD^-0.5 (folded attention scale).
__global__ __launch_bounds__(256, 4) void k_rmsrope(const u16* __restrict__ qkvb,
    const float* __restrict__ cosT, const float* __restrict__ sinT,
    const float* __restrict__ qw, const float* __restrict__ kw,
    u16* __restrict__ qout, u16* __restrict__ kout, u16* __restrict__ vout){
  const int bs = blockIdx.x;
  const int b = bs >> 11, s = bs & 2047;
  const int lane = threadIdx.x & 63, w = threadIdx.x >> 6;
  const u16* row = qkvb + (size_t)bs * 4096;
  const float QS = 0.08838834764831845f;
  const float c1 = cosT[(size_t)bs * 128 + lane];
  const float s1 = sinT[(size_t)bs * 128 + lane];
  const float c2 = cosT[(size_t)bs * 128 + 64 + lane];
  const float s2 = sinT[(size_t)bs * 128 + 64 + lane];
  const float wq1 = qw[lane], wq2 = qw[64 + lane];
  const float wk1 = kw[lane], wk2 = kw[64 + lane];
  for (int u = w; u < 32; u += 4){
    if (u < 24){
      const int isq = (u < 16);
      const int base = isq ? u * 128 : 2048 + (u - 16) * 128;
      float x1 = b2f(row[base + lane]), x2 = b2f(row[base + 64 + lane]);
      float ss = x1 * x1 + x2 * x2;
      #pragma unroll
      for (int m = 1; m < 64; m <<= 1) ss += __shfl_xor(ss, m);
      float rsq = rsqrtf(ss * (1.0f / 128.0f) + 1e-6f);
      float n1 = x1 * rsq * (isq ? wq1 : wk1);
      float n2 = x2 * rsq * (isq ? wq2 : wk2);
      float o1 = n1 * c1 - n2 * s1;
      float o2 = n2 * c2 + n1 * s2;
      if (isq){
        size_t o = ((size_t)(b * 16 + u) * 2048 + s) * 128;
        qout[o + lane] = f2b(o1 * QS); qout[o + 64 + lane] = f2b(o2 * QS);
      } else {
        size_t o = ((size_t)(b * 8 + (u - 16)) * 2048 + s) * 128;
        kout[o + lane] = f2b(o1); kout[o + 64 + lane] = f2b(o2);
      }
    } else {
      const int j = u - 24;
      size_t o = ((size_t)(b * 8 + j) * 2048 + s) * 128;
      vout[o + lane] = row[3072 + j * 128 + lane];
      vout[o + 64 + lane] = row[3072 + j * 128 + 64 + lane];
    }
  }
}

// ---------------- V transpose: [bh][s][d] -> [bh][d][s] (bf16) ----------------
__global__ __launch_bounds__(256, 8) void k_vtrans(const u16* __restrict__ v, u16* __restrict__ vt){
  __shared__ u16 t[64][130];
  const int bid = blockIdx.x;
  const int hd = bid >> 5, sb = bid & 31;
  const u16* src = v + (size_t)hd * 262144 + (size_t)sb * 64 * 128;
  u16* dst = vt + (size_t)hd * 262144 + sb * 64;
  const int tid = threadIdx.x;
  const int r = tid >> 2, c0 = (tid & 3) * 32;
  #pragma unroll
  for (int j = 0; j < 4; ++j)
    *(u16x8*)&t[r][c0 + j * 8] = *(const u16x8*)(src + r * 128 + c0 + j * 8);
  __syncthreads();
  const int d = tid >> 1, s0 = (tid & 1) * 32;
  #pragma unroll
  for (int j = 0; j < 4; ++j){
    u16x8 ov;
    #pragma unroll
    for (int e = 0; e < 8; ++e) ov[e] = t[s0 + j * 8 + e][d];
    *(u16x8*)(dst + (size_t)d * 2048 + s0 + j * 8) = ov;
  }
}

// ---------------- flash attention v7: L2-direct + register software pipeline ----------------
// Same mapping as v6 (512 blocks x 4 independent waves, kvh=bid&7 XCD-pinned KV,
// fixed-shift softmax, zero LDS / zero barriers). New: K fragments double-buffered
// in registers (prefetch tile kt+1 before computing kt -> L2 latency hidden) and
// QK^T accumulated in TWO independent MFMA chains (halves dependent-latency).
__global__ __launch_bounds__(256, 2) void k_attn(const u16* __restrict__ qb, const u16* __restrict__ kb,
                                                 const u16* __restrict__ vtb, u16* __restrict__ ob){
  const int tid = threadIdx.x, lane = tid & 63, w = tid >> 6;
  const int hi = lane >> 5, l31 = lane & 31;
  const int bid = blockIdx.x;
  const int bh = bid & 31;
  const int kvh = bh & 7, r2 = bh >> 3;
  const int b = r2 >> 1, h = kvh * 2 + (r2 & 1);
  const int j = bid >> 5;                       // 0..15
  const int qg = (j < 8) ? j : 23 - j;          // balanced swizzle
  const int t = qg * 4 + w;                     // q-tile (32 rows), 0..63
  const u16* Q  = qb  + ((size_t)(b * 16 + h) * 2048 + t * 32) * 128;
  const u16* Kg = kb  + ((size_t)(b * 8 + kvh) * 2048) * 128;
  const u16* Vt = vtb + ((size_t)(b * 8 + kvh) * 128) * 2048;

  s16x8 qf[8];
  #pragma unroll
  for (int ds = 0; ds < 8; ++ds)
    qf[ds] = *(const s16x8*)(Q + (size_t)l31 * 128 + ds * 16 + hi * 8);

  f32x16 acc[4] = {};
  float lsum = 0.f;
  const int nkt = t + 1;

  s16x8 kfA[8], kfB[8];

  auto loadK = [&](int kt, s16x8* kf){
    const u16* kp = Kg + (size_t)(kt * 32 + l31) * 128 + hi * 8;
    #pragma unroll
    for (int ds = 0; ds < 8; ++ds) kf[ds] = *(const s16x8*)(kp + ds * 16);
  };

  auto compute = [&](int kt, const s16x8* kf, bool dm){
    // V fragments: issue first, consumed after QK+softmax (~500 cyc later)
    s16x8 vf[4][2];
    #pragma unroll
    for (int db = 0; db < 4; ++db)
      #pragma unroll
      for (int ks = 0; ks < 2; ++ks)
        vf[db][ks] = *(const s16x8*)(Vt + (size_t)(db * 32 + l31) * 2048 + kt * 32 + ks * 16 + hi * 8);
    // QK^T: two independent accumulation chains
    f32x16 se = {}, so = {};
    #pragma unroll
    for (int ds = 0; ds < 8; ds += 2){
      MFMA32(se, kf[ds],     qf[ds]);
      MFMA32(so, kf[ds + 1], qf[ds + 1]);
    }
    // fixed-shift softmax: P = exp(s - 20) (Q pre-scaled upstream)
    float p[16];
    float rs = 0.f;
    #pragma unroll
    for (int r = 0; r < 16; ++r){
      float s = se[r] + so[r];
      if (dm){
        const int krow = (r & 3) + 8 * (r >> 2) + 4 * hi;
        if (krow > l31) s = -1e30f;
      }
      p[r] = __expf(s - 20.f);
      rs += p[r];
    }
    lsum += rs;
    // pack P to bf16 A-frags + PV (4 independent chains)
    s16x8 pa[2];
    #pragma unroll
    for (int s = 0; s < 2; ++s){
      const int t8 = s * 8;
      unsigned w0, w1, w2, w3;
      asm("v_cvt_pk_bf16_f32 %0, %1, %2" : "=v"(w0) : "v"(p[t8+0]), "v"(p[t8+1]));
      asm("v_cvt_pk_bf16_f32 %0, %1, %2" : "=v"(w1) : "v"(p[t8+2]), "v"(p[t8+3]));
      asm("v_cvt_pk_bf16_f32 %0, %1, %2" : "=v"(w2) : "v"(p[t8+4]), "v"(p[t8+5]));
      asm("v_cvt_pk_bf16_f32 %0, %1, %2" : "=v"(w3) : "v"(p[t8+6]), "v"(p[t8+7]));
      asm("v_permlane32_swap_b32 %0, %1" : "+v"(w0), "+v"(w2));
      asm("v_permlane32_swap_b32 %0, %1" : "+v"(w1), "+v"(w3));
      u32x4 pw = {w0, w1, w2, w3};
      pa[s] = __builtin_bit_cast(s16x8, pw);
    }
    #pragma unroll
    for (int db = 0; db < 4; ++db)
      #pragma unroll
      for (int ks = 0; ks < 2; ++ks)
        MFMA32(acc[db], pa[ks], vf[db][ks]);
  };

  loadK(0, kfA);
  for (int kt = 0; kt < nkt; kt += 2){
    if (kt + 1 < nkt) loadK(kt + 1, kfB);      // prefetch next into B
    compute(kt, kfA, kt == t);
    if (kt + 1 < nkt){
      if (kt + 2 < nkt) loadK(kt + 2, kfA);    // prefetch next-next into A
      compute(kt + 1, kfB, (kt + 1) == t);
    }
  }

  // ---- epilogue ----
  lsum += __shfl_xor(lsum, 32);
  float li[16];
  #pragma unroll
  for (int r = 0; r < 16; ++r)
    li[r] = __shfl(lsum, (r & 3) + 8 * (r >> 2) + 4 * hi);
  #pragma unroll
  for (int db = 0; db < 4; ++db)
    #pragma unroll
    for (int r = 0; r < 16; ++r){
      const int row = t * 32 + (r & 3) + 8 * (r >> 2) + 4 * hi;
      const int col = h * 128 + db * 32 + l31;
      ob[((size_t)(b * 2048) + row) * 2048 + col] = f2b(acc[db][r] / li[r]);
    }
}

extern "C" void kernel_launch(void* const* d_in, const int* in_sizes, int n_in,
                              void* d_out, int out_size, void* d_ws, size_t ws_size,
                              hipStream_t stream){
  const float* hs   = (const float*)d_in[0];
  const float* cosT = (const float*)d_in[1];
  const float* sinT = (const float*)d_in[2];
  const float* Wq = (const float*)d_in[4];
  const float* Wk = (const float*)d_in[5];
  const float* Wv = (const float*)d_in[6];
  const float* Wo = (const float*)d_in[7];
  const float* qw = (const float*)d_in[8];
  const float* kw = (const float*)d_in[9];
  float* out = (float*)d_out;
  char* ws = (char*)d_ws;

  u16*   hsb   = (u16*)(ws);                         // 16 MB (later: q bf16)
  u16*   wqkvT = (u16*)(ws + 16777216);              // 16 MB (later: k,v bf16)
  u16*   woT   = (u16*)(ws + 33554432);              // 8 MB
  u16*   qkvb  = (u16*)(ws + 41943040);              // 32 MB bf16 (freed after rmsrope)
  u16*   qb    = hsb;
  u16*   kb2   = (u16*)(ws + 16777216);
  u16*   vb2   = (u16*)(ws + 16777216 + 8388608);
  u16*   attnb = (u16*)(ws + 41943040);              // 16 MB (aliases dead qkvb lo)
  u16*   vtb   = (u16*)(ws + 41943040 + 16777216);   // 8 MB  (aliases dead qkvb hi)

  k_cast<<<4096, 256, 0, stream>>>(hs, hsb, 1048576);
  k_transpose<<<dim3(64, 64),  256, 0, stream>>>(Wq, wqkvT,                       2048, 2048);
  k_transpose<<<dim3(32, 64),  256, 0, stream>>>(Wk, wqkvT + (size_t)2048 * 2048, 2048, 1024);
  k_transpose<<<dim3(32, 64),  256, 0, stream>>>(Wv, wqkvT + (size_t)3072 * 2048, 2048, 1024);
  k_transpose<<<dim3(64, 64),  256, 0, stream>>>(Wo, woT,                         2048, 2048);
  k_gemm8<4, true><<<dim3(16, 16), 512, 0, stream>>>(hsb, wqkvT, qkvb, 4096, 4096, 2048);
  k_rmsrope<<<4096, 256, 0, stream>>>(qkvb, cosT, sinT, qw, kw, qb, kb2, vb2);
  k_vtrans<<<512, 256, 0, stream>>>(vb2, vtb);
  k_attn<<<512, 256, 0, stream>>>(qb, kb2, vtb, attnb);
  k_gemm8<2, false><<<dim3(16, 16), 512, 0, stream>>>(attnb, woT, out, 4096, 2048, 2048);
}

// Round 11
// 209.568 us; speedup vs baseline: 1.3634x; 1.3634x over previous
//
#include <hip/hip_runtime.h>

typedef unsigned short u16;
typedef unsigned short u16x8 __attribute__((ext_vector_type(8)));
typedef unsigned short u16x4 __attribute__((ext_vector_type(4)));
typedef short s16x8 __attribute__((ext_vector_type(8)));
typedef float f32x4 __attribute__((ext_vector_type(4)));
typedef float f32x16 __attribute__((ext_vector_type(16)));
typedef unsigned u32x4 __attribute__((ext_vector_type(4)));

__device__ __forceinline__ u16 f2b(float f){
  unsigned u = __builtin_bit_cast(unsigned, f);
  u += 0x7fffu + ((u >> 16) & 1u);
  return (u16)(u >> 16);
}
__device__ __forceinline__ float b2f(u16 v){
  unsigned u = ((unsigned)v) << 16;
  return __builtin_bit_cast(float, u);
}

#define MFMA16(c, a, b) (c) = __builtin_amdgcn_mfma_f32_16x16x32_bf16((a), (b), (c), 0, 0, 0)
#define MFMA32(c, a, b) (c) = __builtin_amdgcn_mfma_f32_32x32x16_bf16((a), (b), (c), 0, 0, 0)

__device__ __forceinline__ void gl16(const u16* g, char* l){
  __builtin_amdgcn_global_load_lds((const __attribute__((address_space(1))) void*)g,
                                   (__attribute__((address_space(3))) void*)l, 16, 0, 0);
}

// ---------------- cast hidden_states f32 -> bf16 ----------------
__global__ void k_cast(const float* __restrict__ src, u16* __restrict__ dst, int n8){
  int i = blockIdx.x * blockDim.x + threadIdx.x;
  if (i >= n8) return;
  const float4* s = (const float4*)(src + (size_t)i * 8);
  float4 a = s[0], b = s[1];
  u16x8 o;
  o[0]=f2b(a.x); o[1]=f2b(a.y); o[2]=f2b(a.z); o[3]=f2b(a.w);
  o[4]=f2b(b.x); o[5]=f2b(b.y); o[6]=f2b(b.z); o[7]=f2b(b.w);
  *(u16x8*)(dst + (size_t)i * 8) = o;
}

// ------- all 4 weight transposes in ONE launch (region-decoded) -------
__global__ void k_transall(const float* __restrict__ Wq, const float* __restrict__ Wk,
                           const float* __restrict__ Wv, const float* __restrict__ Wo,
                           u16* __restrict__ wqkvT, u16* __restrict__ woT){
  __shared__ float t[32][33];
  int by = blockIdx.y;
  const float* src; u16* dst; int N;
  if (by < 64)       { src = Wq; dst = wqkvT;                        N = 2048; }
  else if (by < 128) { src = Wk; dst = wqkvT + (size_t)2048 * 2048;  N = 1024; by -= 64; }
  else if (by < 192) { src = Wv; dst = wqkvT + (size_t)3072 * 2048;  N = 1024; by -= 128; }
  else               { src = Wo; dst = woT;                          N = 2048; by -= 192; }
  int n0 = blockIdx.x * 32, k0 = by * 32;
  if (n0 >= N) return;
  int c = threadIdx.x & 31, r4 = threadIdx.x >> 5;
  #pragma unroll
  for (int p = 0; p < 4; ++p){
    int r = r4 + p * 8;
    t[r][c] = src[(size_t)(k0 + r) * N + n0 + c];
  }
  __syncthreads();
  #pragma unroll
  for (int p = 0; p < 4; ++p){
    int r = r4 + p * 8;
    dst[(size_t)(n0 + r) * 2048 + k0 + c] = f2b(t[c][r]);
  }
}

// ---------------- 8-phase GEMM: C = A(MxK) * BT(NxK)^T ----------------
// MODE 0: plain f32 C.  MODE 1: fused RMSNorm+RoPE+QKV-split epilogue
// (requires N=4096, BN=256: each block owns 2 complete heads x 256 tokens).
template<int NREP, int MODE>
__global__ __launch_bounds__(512, 1) void k_gemm8(const u16* __restrict__ A, const u16* __restrict__ BT,
                                                  float* __restrict__ Cv, int M, int N, int K,
                                                  u16* __restrict__ qout, u16* __restrict__ kout,
                                                  u16* __restrict__ vout,
                                                  const float* __restrict__ cosT, const float* __restrict__ sinT,
                                                  const float* __restrict__ qw, const float* __restrict__ kw){
  constexpr int NH = NREP / 2;
  constexpr int BROWS = NREP * 32;
  constexpr int BLOADS = NREP / 2;
  constexpr int TOT = 4 + 2 * BLOADS;
  constexpr int SMEM = 65536 + 2 * 2 * BROWS * 64 * 2;
  __shared__ __align__(128) char smem[SMEM];
  u16* sAp = (u16*)smem;                    // [2][2][8192]
  u16* sBp = (u16*)(smem + 65536);          // [2][2][BROWS*64]
  const int tid = threadIdx.x;
  const int lane = tid & 63, w = tid >> 6;
  const int l15 = lane & 15, l4 = lane >> 4;
  const int sx = l15 & 7;
  const int wr = w >> 2, wc = w & 3;
  const int m0 = blockIdx.y * 256, n0 = blockIdx.x * (NREP * 64);
  const int nk = K >> 6;

  f32x4 acc[8][NREP];
  #pragma unroll
  for (int mi = 0; mi < 8; ++mi)
    #pragma unroll
    for (int ni = 0; ni < NREP; ++ni) acc[mi][ni] = (f32x4){0.f, 0.f, 0.f, 0.f};

  auto stageA = [&](int d, int half, int k0){
    #pragma unroll
    for (int j = 0; j < 2; ++j){
      const int q = j * 512 + tid;
      const int r = q >> 3, cc = q & 7;
      gl16(A + (size_t)(m0 + half * 128 + r) * K + k0 + ((cc ^ (r & 7)) << 3),
           (char*)(sAp + (d * 2 + half) * 8192) + j * 8192 + (tid >> 6) * 1024);
    }
  };
  auto stageB = [&](int d, int half, int k0){
    #pragma unroll
    for (int j = 0; j < BLOADS; ++j){
      const int q = j * 512 + tid;
      const int r = q >> 3, cc = q & 7;
      gl16(BT + (size_t)(n0 + half * BROWS + r) * K + k0 + ((cc ^ (r & 7)) << 3),
           (char*)(sBp + (d * 2 + half) * (BROWS * 64)) + j * 8192 + (tid >> 6) * 1024);
    }
  };

  stageA(0, 0, 0); stageA(0, 1, 0); stageB(0, 0, 0); stageB(0, 1, 0);
  stageA(1, 0, 64); stageA(1, 1, 64); stageB(1, 0, 64); stageB(1, 1, 64);
  if constexpr (TOT == 8) asm volatile("s_waitcnt vmcnt(8)" ::: "memory");
  else                    asm volatile("s_waitcnt vmcnt(6)" ::: "memory");
  __builtin_amdgcn_s_barrier();

  const int halfB = wc >> 1;
  const int rb0 = (wc & 1) * (NREP * 16);

  for (int kt = 0; kt < nk; ++kt){
    const int d = kt & 1;
    const bool pre = (kt + 2) < nk;
    const int k0n = (kt + 2) << 6;
    const char* hA = (const char*)(sAp + (d * 2 + wr) * 8192);
    const char* hB = (const char*)(sBp + (d * 2 + halfB) * (BROWS * 64));
    s16x8 aa[4][2], bb0[NH][2], bb1[NH][2];

    #pragma unroll
    for (int mi = 0; mi < 4; ++mi)
      #pragma unroll
      for (int kk = 0; kk < 2; ++kk)
        aa[mi][kk] = *(const s16x8*)(hA + (mi * 16 + l15) * 128 + (((kk * 4 + l4) ^ sx) << 4));
    #pragma unroll
    for (int ni = 0; ni < NH; ++ni)
      #pragma unroll
      for (int kk = 0; kk < 2; ++kk)
        bb0[ni][kk] = *(const s16x8*)(hB + (rb0 + ni * 16 + l15) * 128 + (((kk * 4 + l4) ^ sx) << 4));
    __builtin_amdgcn_s_setprio(1);
    #pragma unroll
    for (int mi = 0; mi < 4; ++mi)
      #pragma unroll
      for (int ni = 0; ni < NH; ++ni)
        #pragma unroll
        for (int kk = 0; kk < 2; ++kk)
          MFMA16(acc[mi][ni], aa[mi][kk], bb0[ni][kk]);
    __builtin_amdgcn_s_setprio(0);

    #pragma unroll
    for (int ni = 0; ni < NH; ++ni)
      #pragma unroll
      for (int kk = 0; kk < 2; ++kk)
        bb1[ni][kk] = *(const s16x8*)(hB + (rb0 + (NH + ni) * 16 + l15) * 128 + (((kk * 4 + l4) ^ sx) << 4));
    __builtin_amdgcn_s_setprio(1);
    #pragma unroll
    for (int mi = 0; mi < 4; ++mi)
      #pragma unroll
      for (int ni = 0; ni < NH; ++ni)
        #pragma unroll
        for (int kk = 0; kk < 2; ++kk)
          MFMA16(acc[mi][NH + ni], aa[mi][kk], bb1[ni][kk]);
    __builtin_amdgcn_s_setprio(0);
    __builtin_amdgcn_s_barrier();

    #pragma unroll
    for (int mi = 0; mi < 4; ++mi)
      #pragma unroll
      for (int kk = 0; kk < 2; ++kk)
        aa[mi][kk] = *(const s16x8*)(hA + ((mi + 4) * 16 + l15) * 128 + (((kk * 4 + l4) ^ sx) << 4));
    if (pre){ stageB(d, 0, k0n); stageB(d, 1, k0n); }
    __builtin_amdgcn_s_setprio(1);
    #pragma unroll
    for (int mi = 0; mi < 4; ++mi)
      #pragma unroll
      for (int ni = 0; ni < NH; ++ni)
        #pragma unroll
        for (int kk = 0; kk < 2; ++kk)
          MFMA16(acc[mi + 4][ni], aa[mi][kk], bb0[ni][kk]);
    __builtin_amdgcn_s_setprio(0);
    __builtin_amdgcn_s_barrier();

    if (pre){ stageA(d, 0, k0n); stageA(d, 1, k0n); }
    __builtin_amdgcn_s_setprio(1);
    #pragma unroll
    for (int mi = 0; mi < 4; ++mi)
      #pragma unroll
      for (int ni = 0; ni < NH; ++ni)
        #pragma unroll
        for (int kk = 0; kk < 2; ++kk)
          MFMA16(acc[mi + 4][NH + ni], aa[mi][kk], bb1[ni][kk]);
    __builtin_amdgcn_s_setprio(0);
    if (kt + 1 < nk){
      if (pre){
        if constexpr (TOT == 8) asm volatile("s_waitcnt vmcnt(8)" ::: "memory");
        else                    asm volatile("s_waitcnt vmcnt(6)" ::: "memory");
      } else {
        asm volatile("s_waitcnt vmcnt(0)" ::: "memory");
      }
      __builtin_amdgcn_s_barrier();
    }
  }

  if constexpr (MODE == 0){
    #pragma unroll
    for (int mi = 0; mi < 8; ++mi)
      #pragma unroll
      for (int ni = 0; ni < NREP; ++ni)
        #pragma unroll
        for (int i = 0; i < 4; ++i){
          const int row = m0 + wr * 128 + mi * 16 + l4 * 4 + i;
          const int col = n0 + wc * (NREP * 16) + ni * 16 + l15;
          Cv[(size_t)row * N + col] = acc[mi][ni][i];
        }
  } else {
    // ===== fused RMSNorm + RoPE + QKV split epilogue =====
    // wave (wr,wc): rows m0+wr*128+mi*16+l4*4+i ; unit u = n0/128 + (wc>>1);
    // half = wc&1 ; d = half*64 + ni*16 + l15. Partner wave = wc^1 (other half).
    const int u    = (n0 >> 7) + (wc >> 1);      // 0..31
    const int half = wc & 1;
    __syncthreads();                              // main-loop LDS dead; regs live
    float ss[32];
    if (u < 24){
      #pragma unroll
      for (int mi = 0; mi < 8; ++mi)
        #pragma unroll
        for (int i = 0; i < 4; ++i){
          float s2 = 0.f;
          #pragma unroll
          for (int ni = 0; ni < 4; ++ni){ float x = acc[mi][ni][i]; s2 += x * x; }
          ss[mi * 4 + i] = s2;
        }
      #pragma unroll
      for (int off = 1; off < 16; off <<= 1)
        #pragma unroll
        for (int r = 0; r < 32; ++r) ss[r] += __shfl_xor(ss[r], off);
      float* sums = (float*)smem;                 // [2][4][128] = 4KB
      if (l15 == 0){
        #pragma unroll
        for (int mi = 0; mi < 8; ++mi)
          #pragma unroll
          for (int i = 0; i < 4; ++i)
            sums[(wr * 4 + wc) * 128 + mi * 16 + l4 * 4 + i] = ss[mi * 4 + i];
      }
    } else {
      // v unit: pure bf16 copy-out (no norm, no rope)
      #pragma unroll
      for (int mi = 0; mi < 8; ++mi)
        #pragma unroll
        for (int ni = 0; ni < 4; ++ni)
          #pragma unroll
          for (int i = 0; i < 4; ++i){
            const int rowi = m0 + wr * 128 + mi * 16 + l4 * 4 + i;
            const int b_ = rowi >> 11, s_ = rowi & 2047;
            const int d = half * 64 + ni * 16 + l15;
            vout[((size_t)(b_ * 8 + (u - 24)) * 2048 + s_) * 128 + d] = f2b(acc[mi][ni][i]);
          }
    }
    __syncthreads();
    if (u < 24){
      const float* sums = (const float*)smem;
      #pragma unroll
      for (int mi = 0; mi < 8; ++mi)
        #pragma unroll
        for (int i = 0; i < 4; ++i){
          float tot = ss[mi * 4 + i] + sums[(wr * 4 + (wc ^ 1)) * 128 + mi * 16 + l4 * 4 + i];
          ss[mi * 4 + i] = rsqrtf(tot * (1.0f / 128.0f) + 1e-6f);
        }
      const float* wvp = (u < 16) ? qw : kw;
      float wn[4];
      #pragma unroll
      for (int ni = 0; ni < 4; ++ni) wn[ni] = wvp[half * 64 + ni * 16 + l15];
      #pragma unroll
      for (int mi = 0; mi < 8; ++mi)
        #pragma unroll
        for (int ni = 0; ni < 4; ++ni)
          #pragma unroll
          for (int i = 0; i < 4; ++i)
            acc[mi][ni][i] *= ss[mi * 4 + i] * wn[ni];
    }
    __syncthreads();                              // sums region free
    u16* scr = (u16*)smem;                        // [wr][wc][mi][ni][64 lanes x 4]
    if (u < 24){
      #pragma unroll
      for (int mi = 0; mi < 8; ++mi)
        #pragma unroll
        for (int ni = 0; ni < 4; ++ni){
          u16x4 pk;
          #pragma unroll
          for (int i = 0; i < 4; ++i) pk[i] = f2b(acc[mi][ni][i]);
          *(u16x4*)(scr + ((((wr * 4 + wc) * 8 + mi) * 4 + ni) * 256) + (l4 * 16 + l15) * 4) = pk;
        }
    }
    __syncthreads();
    if (u < 24){
      #pragma unroll
      for (int mi = 0; mi < 8; ++mi){
        #pragma unroll
        for (int ni = 0; ni < 4; ++ni){
          u16x4 pk = *(const u16x4*)(scr + ((((wr * 4 + (wc ^ 1)) * 8 + mi) * 4 + ni) * 256) + (l4 * 16 + l15) * 4);
          const int d = half * 64 + ni * 16 + l15;
          #pragma unroll
          for (int i = 0; i < 4; ++i){
            const int rowi = m0 + wr * 128 + mi * 16 + l4 * 4 + i;
            const int b_ = rowi >> 11, s_ = rowi & 2047;
            const float cs = cosT[(size_t)rowi * 128 + d];
            const float sn = sinT[(size_t)rowi * 128 + d];
            const float self = acc[mi][ni][i];
            const float part = b2f(pk[i]);
            const float o = half ? (self * cs + part * sn) : (self * cs - part * sn);
            if (u < 16) qout[((size_t)(b_ * 16 + u) * 2048 + s_) * 128 + d] = f2b(o);
            else        kout[((size_t)(b_ * 8 + (u - 16)) * 2048 + s_) * 128 + d] = f2b(o);
          }
        }
      }
    }
  }
}

// ---------------- V transpose: [bh][s][d] -> [bh][d][s] (bf16) ----------------
__global__ __launch_bounds__(256, 8) void k_vtrans(const u16* __restrict__ v, u16* __restrict__ vt){
  __shared__ u16 t[64][130];
  const int bid = blockIdx.x;
  const int hd = bid >> 5, sb = bid & 31;
  const u16* src = v + (size_t)hd * 262144 + (size_t)sb * 64 * 128;
  u16* dst = vt + (size_t)hd * 262144 + sb * 64;
  const int tid = threadIdx.x;
  const int r = tid >> 2, c0 = (tid & 3) * 32;
  #pragma unroll
  for (int j = 0; j < 4; ++j)
    *(u16x8*)&t[r][c0 + j * 8] = *(const u16x8*)(src + r * 128 + c0 + j * 8);
  __syncthreads();
  const int d = tid >> 1, s0 = (tid & 1) * 32;
  #pragma unroll
  for (int j = 0; j < 4; ++j){
    u16x8 ov;
    #pragma unroll
    for (int e = 0; e < 8; ++e) ov[e] = t[s0 + j * 8 + e][d];
    *(u16x8*)(dst + (size_t)d * 2048 + s0 + j * 8) = ov;
  }
}

// ---------------- flash attention v4 (round-6 verbatim: 80us known-good) ----------------
__device__ __forceinline__ void stage_kv(const u16* __restrict__ Kg, const u16* __restrict__ Vt,
                                         int kt, u16* sKb, u16* sVb, int tid){
  #pragma unroll
  for (int i = 0; i < 4; ++i){
    const int off = i * 4096 + tid * 16;
    const unsigned wub = (unsigned)(i * 4096 + (tid >> 6) * 1024);
    const int key = off >> 8, ks = (off >> 4) & 15;
    __builtin_amdgcn_global_load_lds(
        (const __attribute__((address_space(1))) void*)(Kg + (size_t)(kt * 64 + key) * 128 + ((ks ^ (key & 15)) << 3)),
        (__attribute__((address_space(3))) void*)((char*)sKb + wub), 16, 0, 0);
    const int d = off >> 7, vs = (off >> 4) & 7;
    __builtin_amdgcn_global_load_lds(
        (const __attribute__((address_space(1))) void*)(Vt + (size_t)d * 2048 + kt * 64 + ((vs ^ (d & 7)) << 3)),
        (__attribute__((address_space(3))) void*)((char*)sVb + wub), 16, 0, 0);
  }
}

__global__ __launch_bounds__(256, 2) void k_attn(const u16* __restrict__ qb, const u16* __restrict__ kb,
                                                 const u16* __restrict__ vtb, u16* __restrict__ ob){
  __shared__ __align__(128) u16 sK[2][64 * 128];
  __shared__ __align__(128) u16 sV[2][128 * 64];
  const int tid = threadIdx.x, lane = tid & 63, w = tid >> 6;
  const int hi = lane >> 5, l31 = lane & 31;
  const int bid = blockIdx.x;
  const int bh = bid & 31;
  const int kvh = bh & 7, r2 = bh >> 3;
  const int b = r2 >> 1, h = kvh * 2 + (r2 & 1);
  const int slot = bid >> 5;
  const int qt = (slot < 8) ? (15 - 2 * slot) : (2 * slot - 16);
  const u16* Q  = qb  + ((size_t)(b * 16 + h)  * 2048) * 128;
  const u16* Kg = kb  + ((size_t)(b * 8 + kvh) * 2048) * 128;
  const u16* Vt = vtb + ((size_t)(b * 8 + kvh) * 128) * 2048;
  const int qrow0 = qt * 128 + w * 32;

  s16x8 qf[8];
  #pragma unroll
  for (int ds = 0; ds < 8; ++ds)
    qf[ds] = *(const s16x8*)(Q + (size_t)(qrow0 + l31) * 128 + ds * 16 + hi * 8);

  f32x16 acc[4] = {};
  float mx = -1e30f, lsum = 0.f;
  const int nkt = qt * 2 + 2;

  stage_kv(Kg, Vt, 0, sK[0], sV[0], tid);
  for (int kt = 0; kt < nkt; ++kt){
    const int cur = kt & 1;
    if (kt + 1 < nkt){
      stage_kv(Kg, Vt, kt + 1, sK[cur ^ 1], sV[cur ^ 1], tid);
      asm volatile("s_waitcnt vmcnt(8)");
    } else {
      asm volatile("s_waitcnt vmcnt(0)");
    }
    __builtin_amdgcn_s_barrier();

    if (kt * 64 <= qrow0 + 31){
      const char* sKc = (const char*)sK[cur];
      const char* sVc = (const char*)sV[cur];
      f32x16 s0 = {}, s1 = {};
      #pragma unroll
      for (int ds = 0; ds < 8; ++ds){
        const int sl = ((ds * 2 + hi) ^ (l31 & 15)) << 4;
        s16x8 k0 = *(const s16x8*)(sKc + l31 * 256 + sl);
        s16x8 k1 = *(const s16x8*)(sKc + 8192 + l31 * 256 + sl);
        MFMA32(s0, k0, qf[ds]);
        MFMA32(s1, k1, qf[ds]);
      }
      const int qg = qrow0 + l31;
      const bool domask = (kt * 64 + 63) > qrow0;
      float pv0[16], pv1[16];
      float pmax = -1e30f;
      #pragma unroll
      for (int r = 0; r < 16; ++r){
        const int krow = (r & 3) + 8 * (r >> 2) + 4 * hi;
        float v0 = s0[r] * 0.08838834764831845f;
        float v1 = s1[r] * 0.08838834764831845f;
        if (domask){
          if (kt * 64 + krow > qg)      v0 = -1e30f;
          if (kt * 64 + 32 + krow > qg) v1 = -1e30f;
        }
        pv0[r] = v0; pv1[r] = v1;
        pmax = fmaxf(pmax, fmaxf(v0, v1));
      }
      pmax = fmaxf(pmax, __shfl_xor(pmax, 32));
      if (!__all(pmax - mx <= 8.f)){
        const float mn = fmaxf(mx, pmax);
        const float al = __expf(mx - mn);
        mx = mn; lsum *= al;
        #pragma unroll
        for (int r = 0; r < 16; ++r){
          const float ar = __shfl(al, (r & 3) + 8 * (r >> 2) + 4 * hi);
          acc[0][r] *= ar; acc[1][r] *= ar; acc[2][r] *= ar; acc[3][r] *= ar;
        }
      }
      float rs = 0.f;
      #pragma unroll
      for (int r = 0; r < 16; ++r){
        const float e0 = __expf(pv0[r] - mx);
        const float e1 = __expf(pv1[r] - mx);
        pv0[r] = e0; pv1[r] = e1;
        rs += e0 + e1;
      }
      rs += __shfl_xor(rs, 32);
      lsum += rs;
      #pragma unroll
      for (int s = 0; s < 4; ++s){
        const int t8 = (s & 1) * 8;
        unsigned w0, w1, w2, w3;
        if (s < 2){
          asm("v_cvt_pk_bf16_f32 %0, %1, %2" : "=v"(w0) : "v"(pv0[t8+0]), "v"(pv0[t8+1]));
          asm("v_cvt_pk_bf16_f32 %0, %1, %2" : "=v"(w1) : "v"(pv0[t8+2]), "v"(pv0[t8+3]));
          asm("v_cvt_pk_bf16_f32 %0, %1, %2" : "=v"(w2) : "v"(pv0[t8+4]), "v"(pv0[t8+5]));
          asm("v_cvt_pk_bf16_f32 %0, %1, %2" : "=v"(w3) : "v"(pv0[t8+6]), "v"(pv0[t8+7]));
        } else {
          asm("v_cvt_pk_bf16_f32 %0, %1, %2" : "=v"(w0) : "v"(pv1[t8+0]), "v"(pv1[t8+1]));
          asm("v_cvt_pk_bf16_f32 %0, %1, %2" : "=v"(w1) : "v"(pv1[t8+2]), "v"(pv1[t8+3]));
          asm("v_cvt_pk_bf16_f32 %0, %1, %2" : "=v"(w2) : "v"(pv1[t8+4]), "v"(pv1[t8+5]));
          asm("v_cvt_pk_bf16_f32 %0, %1, %2" : "=v"(w3) : "v"(pv1[t8+6]), "v"(pv1[t8+7]));
        }
        asm("v_permlane32_swap_b32 %0, %1" : "+v"(w0), "+v"(w2));
        asm("v_permlane32_swap_b32 %0, %1" : "+v"(w1), "+v"(w3));
        u32x4 pw = {w0, w1, w2, w3};
        s16x8 pa = __builtin_bit_cast(s16x8, pw);
        #pragma unroll
        for (int db = 0; db < 4; ++db){
          const int d = db * 32 + l31;
          s16x8 vf = *(const s16x8*)(sVc + d * 128 + (((s * 2 + hi) ^ (d & 7)) << 4));
          MFMA32(acc[db], pa, vf);
        }
      }
    }
    asm volatile("s_waitcnt lgkmcnt(0)");
    __builtin_amdgcn_s_barrier();
  }
  float li[16];
  #pragma unroll
  for (int r = 0; r < 16; ++r)
    li[r] = __shfl(lsum, (r & 3) + 8 * (r >> 2) + 4 * hi);
  #pragma unroll
  for (int db = 0; db < 4; ++db)
    #pragma unroll
    for (int r = 0; r < 16; ++r){
      const int row = qrow0 + (r & 3) + 8 * (r >> 2) + 4 * hi;
      const int col = h * 128 + db * 32 + l31;
      ob[((size_t)(b * 2048) + row) * 2048 + col] = f2b(acc[db][r] / li[r]);
    }
}

extern "C" void kernel_launch(void* const* d_in, const int* in_sizes, int n_in,
                              void* d_out, int out_size, void* d_ws, size_t ws_size,
                              hipStream_t stream){
  const float* hs   = (const float*)d_in[0];
  const float* cosT = (const float*)d_in[1];
  const float* sinT = (const float*)d_in[2];
  const float* Wq = (const float*)d_in[4];
  const float* Wk = (const float*)d_in[5];
  const float* Wv = (const float*)d_in[6];
  const float* Wo = (const float*)d_in[7];
  const float* qw = (const float*)d_in[8];
  const float* kw = (const float*)d_in[9];
  float* out = (float*)d_out;
  char* ws = (char*)d_ws;

  // workspace layout (96 MB, NO aliasing between gemm1 inputs and outputs)
  u16* hsb   = (u16*)(ws);                       // 16 MB  hs bf16
  u16* wqkvT = (u16*)(ws + ((size_t)16 << 20));  // 16 MB
  u16* woT   = (u16*)(ws + ((size_t)32 << 20));  //  8 MB
  u16* qb    = (u16*)(ws + ((size_t)40 << 20));  // 16 MB
  u16* kb2   = (u16*)(ws + ((size_t)56 << 20));  //  8 MB
  u16* vb2   = (u16*)(ws + ((size_t)64 << 20));  //  8 MB
  u16* vtb   = (u16*)(ws + ((size_t)72 << 20));  //  8 MB
  u16* attnb = (u16*)(ws + ((size_t)80 << 20));  // 16 MB

  k_cast<<<4096, 256, 0, stream>>>(hs, hsb, 1048576);
  k_transall<<<dim3(64, 256), 256, 0, stream>>>(Wq, Wk, Wv, Wo, wqkvT, woT);
  k_gemm8<4, 1><<<dim3(16, 16), 512, 0, stream>>>(hsb, wqkvT, nullptr, 4096, 4096, 2048,
                                                  qb, kb2, vb2, cosT, sinT, qw, kw);
  k_vtrans<<<512, 256, 0, stream>>>(vb2, vtb);
  k_attn<<<512, 256, 0, stream>>>(qb, kb2, vtb, attnb);
  k_gemm8<2, 0><<<dim3(16, 16), 512, 0, stream>>>(attnb, woT, (float*)out, 4096, 2048, 2048,
                                                  nullptr, nullptr, nullptr, nullptr, nullptr, nullptr, nullptr);
}

// Round 12
// 203.767 us; speedup vs baseline: 1.4022x; 1.0285x over previous
//
#include <hip/hip_runtime.h>

typedef unsigned short u16;
typedef unsigned short u16x8 __attribute__((ext_vector_type(8)));
typedef unsigned short u16x4 __attribute__((ext_vector_type(4)));
typedef short s16x8 __attribute__((ext_vector_type(8)));
typedef float f32x4 __attribute__((ext_vector_type(4)));
typedef float f32x16 __attribute__((ext_vector_type(16)));
typedef unsigned u32x4 __attribute__((ext_vector_type(4)));

__device__ __forceinline__ u16 f2b(float f){
  unsigned u = __builtin_bit_cast(unsigned, f);
  u += 0x7fffu + ((u >> 16) & 1u);
  return (u16)(u >> 16);
}
__device__ __forceinline__ float b2f(u16 v){
  unsigned u = ((unsigned)v) << 16;
  return __builtin_bit_cast(float, u);
}

#define MFMA16(c, a, b) (c) = __builtin_amdgcn_mfma_f32_16x16x32_bf16((a), (b), (c), 0, 0, 0)
#define MFMA32(c, a, b) (c) = __builtin_amdgcn_mfma_f32_32x32x16_bf16((a), (b), (c), 0, 0, 0)

__device__ __forceinline__ void gl16(const u16* g, char* l){
  __builtin_amdgcn_global_load_lds((const __attribute__((address_space(1))) void*)g,
                                   (__attribute__((address_space(3))) void*)l, 16, 0, 0);
}

// ---------------- cast hidden_states f32 -> bf16 ----------------
__global__ void k_cast(const float* __restrict__ src, u16* __restrict__ dst, int n8){
  int i = blockIdx.x * blockDim.x + threadIdx.x;
  if (i >= n8) return;
  const float4* s = (const float4*)(src + (size_t)i * 8);
  float4 a = s[0], b = s[1];
  u16x8 o;
  o[0]=f2b(a.x); o[1]=f2b(a.y); o[2]=f2b(a.z); o[3]=f2b(a.w);
  o[4]=f2b(b.x); o[5]=f2b(b.y); o[6]=f2b(b.z); o[7]=f2b(b.w);
  *(u16x8*)(dst + (size_t)i * 8) = o;
}

// ------- all 4 weight transposes in ONE launch (region-decoded) -------
__global__ void k_transall(const float* __restrict__ Wq, const float* __restrict__ Wk,
                           const float* __restrict__ Wv, const float* __restrict__ Wo,
                           u16* __restrict__ wqkvT, u16* __restrict__ woT){
  __shared__ float t[32][33];
  int by = blockIdx.y;
  const float* src; u16* dst; int N;
  if (by < 64)       { src = Wq; dst = wqkvT;                        N = 2048; }
  else if (by < 128) { src = Wk; dst = wqkvT + (size_t)2048 * 2048;  N = 1024; by -= 64; }
  else if (by < 192) { src = Wv; dst = wqkvT + (size_t)3072 * 2048;  N = 1024; by -= 128; }
  else               { src = Wo; dst = woT;                          N = 2048; by -= 192; }
  int n0 = blockIdx.x * 32, k0 = by * 32;
  if (n0 >= N) return;
  int c = threadIdx.x & 31, r4 = threadIdx.x >> 5;
  #pragma unroll
  for (int p = 0; p < 4; ++p){
    int r = r4 + p * 8;
    t[r][c] = src[(size_t)(k0 + r) * N + n0 + c];
  }
  __syncthreads();
  #pragma unroll
  for (int p = 0; p < 4; ++p){
    int r = r4 + p * 8;
    dst[(size_t)(n0 + r) * 2048 + k0 + c] = f2b(t[c][r]);
  }
}

// ---------------- 8-phase GEMM: C = A(MxK) * BT(NxK)^T ----------------
// MODE 0: f32 C via LDS-restaged float4 stores (NREP=2 only).
// MODE 1: fused RMSNorm+RoPE+QKV-split epilogue, vectorized u16x8 outputs;
//         v-units written directly in transposed [bh][d][s] layout.
template<int NREP, int MODE>
__global__ __launch_bounds__(512, 1) void k_gemm8(const u16* __restrict__ A, const u16* __restrict__ BT,
                                                  float* __restrict__ Cv, int M, int N, int K,
                                                  u16* __restrict__ qout, u16* __restrict__ kout,
                                                  u16* __restrict__ vout,
                                                  const float* __restrict__ cosT, const float* __restrict__ sinT,
                                                  const float* __restrict__ qw, const float* __restrict__ kw){
  constexpr int NH = NREP / 2;
  constexpr int BROWS = NREP * 32;
  constexpr int BLOADS = NREP / 2;
  constexpr int TOT = 4 + 2 * BLOADS;
  constexpr int SMEM0 = 65536 + 2 * 2 * BROWS * 64 * 2;
  constexpr int SMEM = (SMEM0 > 131072) ? SMEM0 : 131072;   // epilogue out-tile needs 128KB
  __shared__ __align__(128) char smem[SMEM];
  u16* sAp = (u16*)smem;                    // [2][2][8192]
  u16* sBp = (u16*)(smem + 65536);          // [2][2][BROWS*64]
  const int tid = threadIdx.x;
  const int lane = tid & 63, w = tid >> 6;
  const int l15 = lane & 15, l4 = lane >> 4;
  const int sx = l15 & 7;
  const int wr = w >> 2, wc = w & 3;
  const int m0 = blockIdx.y * 256, n0 = blockIdx.x * (NREP * 64);
  const int nk = K >> 6;

  f32x4 acc[8][NREP];
  #pragma unroll
  for (int mi = 0; mi < 8; ++mi)
    #pragma unroll
    for (int ni = 0; ni < NREP; ++ni) acc[mi][ni] = (f32x4){0.f, 0.f, 0.f, 0.f};

  auto stageA = [&](int d, int half, int k0){
    #pragma unroll
    for (int j = 0; j < 2; ++j){
      const int q = j * 512 + tid;
      const int r = q >> 3, cc = q & 7;
      gl16(A + (size_t)(m0 + half * 128 + r) * K + k0 + ((cc ^ (r & 7)) << 3),
           (char*)(sAp + (d * 2 + half) * 8192) + j * 8192 + (tid >> 6) * 1024);
    }
  };
  auto stageB = [&](int d, int half, int k0){
    #pragma unroll
    for (int j = 0; j < BLOADS; ++j){
      const int q = j * 512 + tid;
      const int r = q >> 3, cc = q & 7;
      gl16(BT + (size_t)(n0 + half * BROWS + r) * K + k0 + ((cc ^ (r & 7)) << 3),
           (char*)(sBp + (d * 2 + half) * (BROWS * 64)) + j * 8192 + (tid >> 6) * 1024);
    }
  };

  stageA(0, 0, 0); stageA(0, 1, 0); stageB(0, 0, 0); stageB(0, 1, 0);
  stageA(1, 0, 64); stageA(1, 1, 64); stageB(1, 0, 64); stageB(1, 1, 64);
  if constexpr (TOT == 8) asm volatile("s_waitcnt vmcnt(8)" ::: "memory");
  else                    asm volatile("s_waitcnt vmcnt(6)" ::: "memory");
  __builtin_amdgcn_s_barrier();

  const int halfB = wc >> 1;
  const int rb0 = (wc & 1) * (NREP * 16);

  for (int kt = 0; kt < nk; ++kt){
    const int d = kt & 1;
    const bool pre = (kt + 2) < nk;
    const int k0n = (kt + 2) << 6;
    const char* hA = (const char*)(sAp + (d * 2 + wr) * 8192);
    const char* hB = (const char*)(sBp + (d * 2 + halfB) * (BROWS * 64));
    s16x8 aa[4][2], bb0[NH][2], bb1[NH][2];

    #pragma unroll
    for (int mi = 0; mi < 4; ++mi)
      #pragma unroll
      for (int kk = 0; kk < 2; ++kk)
        aa[mi][kk] = *(const s16x8*)(hA + (mi * 16 + l15) * 128 + (((kk * 4 + l4) ^ sx) << 4));
    #pragma unroll
    for (int ni = 0; ni < NH; ++ni)
      #pragma unroll
      for (int kk = 0; kk < 2; ++kk)
        bb0[ni][kk] = *(const s16x8*)(hB + (rb0 + ni * 16 + l15) * 128 + (((kk * 4 + l4) ^ sx) << 4));
    __builtin_amdgcn_s_setprio(1);
    #pragma unroll
    for (int mi = 0; mi < 4; ++mi)
      #pragma unroll
      for (int ni = 0; ni < NH; ++ni)
        #pragma unroll
        for (int kk = 0; kk < 2; ++kk)
          MFMA16(acc[mi][ni], aa[mi][kk], bb0[ni][kk]);
    __builtin_amdgcn_s_setprio(0);

    #pragma unroll
    for (int ni = 0; ni < NH; ++ni)
      #pragma unroll
      for (int kk = 0; kk < 2; ++kk)
        bb1[ni][kk] = *(const s16x8*)(hB + (rb0 + (NH + ni) * 16 + l15) * 128 + (((kk * 4 + l4) ^ sx) << 4));
    __builtin_amdgcn_s_setprio(1);
    #pragma unroll
    for (int mi = 0; mi < 4; ++mi)
      #pragma unroll
      for (int ni = 0; ni < NH; ++ni)
        #pragma unroll
        for (int kk = 0; kk < 2; ++kk)
          MFMA16(acc[mi][NH + ni], aa[mi][kk], bb1[ni][kk]);
    __builtin_amdgcn_s_setprio(0);
    __builtin_amdgcn_s_barrier();

    #pragma unroll
    for (int mi = 0; mi < 4; ++mi)
      #pragma unroll
      for (int kk = 0; kk < 2; ++kk)
        aa[mi][kk] = *(const s16x8*)(hA + ((mi + 4) * 16 + l15) * 128 + (((kk * 4 + l4) ^ sx) << 4));
    if (pre){ stageB(d, 0, k0n); stageB(d, 1, k0n); }
    __builtin_amdgcn_s_setprio(1);
    #pragma unroll
    for (int mi = 0; mi < 4; ++mi)
      #pragma unroll
      for (int ni = 0; ni < NH; ++ni)
        #pragma unroll
        for (int kk = 0; kk < 2; ++kk)
          MFMA16(acc[mi + 4][ni], aa[mi][kk], bb0[ni][kk]);
    __builtin_amdgcn_s_setprio(0);
    __builtin_amdgcn_s_barrier();

    if (pre){ stageA(d, 0, k0n); stageA(d, 1, k0n); }
    __builtin_amdgcn_s_setprio(1);
    #pragma unroll
    for (int mi = 0; mi < 4; ++mi)
      #pragma unroll
      for (int ni = 0; ni < NH; ++ni)
        #pragma unroll
        for (int kk = 0; kk < 2; ++kk)
          MFMA16(acc[mi + 4][NH + ni], aa[mi][kk], bb1[ni][kk]);
    __builtin_amdgcn_s_setprio(0);
    if (kt + 1 < nk){
      if (pre){
        if constexpr (TOT == 8) asm volatile("s_waitcnt vmcnt(8)" ::: "memory");
        else                    asm volatile("s_waitcnt vmcnt(6)" ::: "memory");
      } else {
        asm volatile("s_waitcnt vmcnt(0)" ::: "memory");
      }
      __builtin_amdgcn_s_barrier();
    }
  }

  if constexpr (MODE == 0){
    // ---- LDS-restaged f32 epilogue: float4 coalesced stores (BN=128) ----
    float* fOut = (float*)smem;
    __syncthreads();
    #pragma unroll
    for (int mi = 0; mi < 8; ++mi)
      #pragma unroll
      for (int ni = 0; ni < NREP; ++ni)
        #pragma unroll
        for (int i = 0; i < 4; ++i){
          const int rl = wr * 128 + mi * 16 + l4 * 4 + i;
          const int cl = wc * (NREP * 16) + ni * 16 + l15;
          fOut[rl * 128 + (cl ^ ((rl & 7) << 2))] = acc[mi][ni][i];
        }
    __syncthreads();
    const int c0 = (tid & 31) * 4;
    const int rb = (tid >> 5) & 15;
    #pragma unroll
    for (int j = 0; j < 16; ++j){
      const int rl = rb + j * 16;
      f32x4 vv = *(const f32x4*)(fOut + rl * 128 + (c0 ^ ((rl & 7) << 2)));
      *(f32x4*)(Cv + (size_t)(m0 + rl) * N + n0 + c0) = vv;
    }
  } else {
    // ===== fused RMSNorm + RoPE + QKV split, vectorized via LDS out-tile =====
    const int u0 = n0 >> 7;                               // first unit (even)
    const int type = (u0 >= 24) ? 2 : ((u0 >= 16) ? 1 : 0);
    const int uiw = wc >> 1;
    const int half = wc & 1;
    u16* sOut = (u16*)smem;
    __syncthreads();
    float ss[32];
    if (type < 2){
      #pragma unroll
      for (int mi = 0; mi < 8; ++mi)
        #pragma unroll
        for (int i = 0; i < 4; ++i){
          float s2 = 0.f;
          #pragma unroll
          for (int ni = 0; ni < 4; ++ni){ float x = acc[mi][ni][i]; s2 += x * x; }
          ss[mi * 4 + i] = s2;
        }
      #pragma unroll
      for (int off = 1; off < 16; off <<= 1)
        #pragma unroll
        for (int r = 0; r < 32; ++r) ss[r] += __shfl_xor(ss[r], off);
      float* sums = (float*)smem;
      if (l15 == 0){
        #pragma unroll
        for (int mi = 0; mi < 8; ++mi)
          #pragma unroll
          for (int i = 0; i < 4; ++i)
            sums[(wr * 4 + wc) * 128 + mi * 16 + l4 * 4 + i] = ss[mi * 4 + i];
      }
    }
    __syncthreads();
    if (type < 2){
      const float* sums = (const float*)smem;
      #pragma unroll
      for (int mi = 0; mi < 8; ++mi)
        #pragma unroll
        for (int i = 0; i < 4; ++i){
          float tot = ss[mi * 4 + i] + sums[(wr * 4 + (wc ^ 1)) * 128 + mi * 16 + l4 * 4 + i];
          ss[mi * 4 + i] = rsqrtf(tot * (1.0f / 128.0f) + 1e-6f);
        }
      const float* wvp = (type == 0) ? qw : kw;
      float wn[4];
      #pragma unroll
      for (int ni = 0; ni < 4; ++ni) wn[ni] = wvp[half * 64 + ni * 16 + l15];
      #pragma unroll
      for (int mi = 0; mi < 8; ++mi)
        #pragma unroll
        for (int ni = 0; ni < 4; ++ni)
          #pragma unroll
          for (int i = 0; i < 4; ++i)
            acc[mi][ni][i] *= ss[mi * 4 + i] * wn[ni];
    }
    __syncthreads();                                      // sums reads done
    if (type < 2){
      // E3 q/k: [ui][row][d], d XOR-swizzled by row
      #pragma unroll
      for (int mi = 0; mi < 8; ++mi)
        #pragma unroll
        for (int ni = 0; ni < 4; ++ni)
          #pragma unroll
          for (int i = 0; i < 4; ++i){
            const int rl = wr * 128 + mi * 16 + l4 * 4 + i;
            const int d  = half * 64 + ni * 16 + l15;
            sOut[(uiw * 256 + rl) * 128 + (d ^ ((rl & 7) << 3))] = f2b(acc[mi][ni][i]);
          }
    } else {
      // E3 v: [ui][d][row], row XOR-swizzled by d; b64 packs the 4 i-rows
      #pragma unroll
      for (int mi = 0; mi < 8; ++mi)
        #pragma unroll
        for (int ni = 0; ni < 4; ++ni){
          const int r0 = wr * 128 + mi * 16 + l4 * 4;
          const int d  = half * 64 + ni * 16 + l15;
          u16x4 pk;
          #pragma unroll
          for (int i = 0; i < 4; ++i) pk[i] = f2b(acc[mi][ni][i]);
          *(u16x4*)(sOut + (uiw * 128 + d) * 256 + (r0 ^ ((d & 15) << 4))) = pk;
        }
    }
    __syncthreads();
    const int b_  = m0 >> 11;
    const int s0_ = m0 & 2047;
    if (type < 2){
      const int uix = tid >> 8;
      const int d0  = (tid & 15) * 8;
      const int rb  = (tid >> 4) & 15;
      const int u_  = u0 + uix;
      const float sg = (d0 < 64) ? -1.f : 1.f;
      u16* outp = (type == 0)
        ? qout + ((size_t)(b_ * 16 + u_) * 2048 + s0_) * 128
        : kout + ((size_t)(b_ * 8 + (u_ - 16)) * 2048 + s0_) * 128;
      #pragma unroll
      for (int j = 0; j < 16; ++j){
        const int rl = rb + j * 16;
        const int rowi = m0 + rl;
        const int sw = (rl & 7) << 3;
        u16x8 xs = *(const u16x8*)(sOut + (uix * 256 + rl) * 128 + (d0 ^ sw));
        u16x8 xp = *(const u16x8*)(sOut + (uix * 256 + rl) * 128 + ((d0 ^ 64) ^ sw));
        const float* cp = cosT + (size_t)rowi * 128 + d0;
        const float* sp = sinT + (size_t)rowi * 128 + d0;
        float4 ca = *(const float4*)cp,  cb = *(const float4*)(cp + 4);
        float4 sa = *(const float4*)sp,  sb = *(const float4*)(sp + 4);
        float cv[8] = {ca.x, ca.y, ca.z, ca.w, cb.x, cb.y, cb.z, cb.w};
        float sv[8] = {sa.x, sa.y, sa.z, sa.w, sb.x, sb.y, sb.z, sb.w};
        u16x8 o;
        #pragma unroll
        for (int e = 0; e < 8; ++e)
          o[e] = f2b(b2f(xs[e]) * cv[e] + sg * b2f(xp[e]) * sv[e]);
        *(u16x8*)(outp + (size_t)rl * 128 + d0) = o;
      }
    } else {
      // E4 v: write transposed [bh][d][s] directly (replaces k_vtrans)
      const int rc = tid & 31;
      const int dq = (tid >> 5) & 15;
      const int r0g = rc * 8;
      #pragma unroll
      for (int ui2 = 0; ui2 < 2; ++ui2){
        const int vh = u0 + ui2 - 24;
        u16* dv = vout + ((size_t)(b_ * 8 + vh) * 128) * 2048 + s0_;
        #pragma unroll
        for (int dl = 0; dl < 8; ++dl){
          const int d = dq * 8 + dl;
          const int r0s = r0g ^ ((d & 15) << 4);
          u16x8 vv = *(const u16x8*)(sOut + (ui2 * 128 + d) * 256 + r0s);
          *(u16x8*)(dv + (size_t)d * 2048 + r0g) = vv;
        }
      }
    }
  }
}

// ---------------- flash attention v4 (known-good ~80us) ----------------
__device__ __forceinline__ void stage_kv(const u16* __restrict__ Kg, const u16* __restrict__ Vt,
                                         int kt, u16* sKb, u16* sVb, int tid){
  #pragma unroll
  for (int i = 0; i < 4; ++i){
    const int off = i * 4096 + tid * 16;
    const unsigned wub = (unsigned)(i * 4096 + (tid >> 6) * 1024);
    const int key = off >> 8, ks = (off >> 4) & 15;
    __builtin_amdgcn_global_load_lds(
        (const __attribute__((address_space(1))) void*)(Kg + (size_t)(kt * 64 + key) * 128 + ((ks ^ (key & 15)) << 3)),
        (__attribute__((address_space(3))) void*)((char*)sKb + wub), 16, 0, 0);
    const int d = off >> 7, vs = (off >> 4) & 7;
    __builtin_amdgcn_global_load_lds(
        (const __attribute__((address_space(1))) void*)(Vt + (size_t)d * 2048 + kt * 64 + ((vs ^ (d & 7)) << 3)),
        (__attribute__((address_space(3))) void*)((char*)sVb + wub), 16, 0, 0);
  }
}

__global__ __launch_bounds__(256, 2) void k_attn(const u16* __restrict__ qb, const u16* __restrict__ kb,
                                                 const u16* __restrict__ vtb, u16* __restrict__ ob){
  __shared__ __align__(128) u16 sK[2][64 * 128];
  __shared__ __align__(128) u16 sV[2][128 * 64];
  const int tid = threadIdx.x, lane = tid & 63, w = tid >> 6;
  const int hi = lane >> 5, l31 = lane & 31;
  const int bid = blockIdx.x;
  const int bh = bid & 31;
  const int kvh = bh & 7, r2 = bh >> 3;
  const int b = r2 >> 1, h = kvh * 2 + (r2 & 1);
  const int slot = bid >> 5;
  const int qt = (slot < 8) ? (15 - 2 * slot) : (2 * slot - 16);
  const u16* Q  = qb  + ((size_t)(b * 16 + h)  * 2048) * 128;
  const u16* Kg = kb  + ((size_t)(b * 8 + kvh) * 2048) * 128;
  const u16* Vt = vtb + ((size_t)(b * 8 + kvh) * 128) * 2048;
  const int qrow0 = qt * 128 + w * 32;

  s16x8 qf[8];
  #pragma unroll
  for (int ds = 0; ds < 8; ++ds)
    qf[ds] = *(const s16x8*)(Q + (size_t)(qrow0 + l31) * 128 + ds * 16 + hi * 8);

  f32x16 acc[4] = {};
  float mx = -1e30f, lsum = 0.f;
  const int nkt = qt * 2 + 2;

  stage_kv(Kg, Vt, 0, sK[0], sV[0], tid);
  for (int kt = 0; kt < nkt; ++kt){
    const int cur = kt & 1;
    if (kt + 1 < nkt){
      stage_kv(Kg, Vt, kt + 1, sK[cur ^ 1], sV[cur ^ 1], tid);
      asm volatile("s_waitcnt vmcnt(8)");
    } else {
      asm volatile("s_waitcnt vmcnt(0)");
    }
    __builtin_amdgcn_s_barrier();

    if (kt * 64 <= qrow0 + 31){
      const char* sKc = (const char*)sK[cur];
      const char* sVc = (const char*)sV[cur];
      f32x16 s0 = {}, s1 = {};
      #pragma unroll
      for (int ds = 0; ds < 8; ++ds){
        const int sl = ((ds * 2 + hi) ^ (l31 & 15)) << 4;
        s16x8 k0 = *(const s16x8*)(sKc + l31 * 256 + sl);
        s16x8 k1 = *(const s16x8*)(sKc + 8192 + l31 * 256 + sl);
        MFMA32(s0, k0, qf[ds]);
        MFMA32(s1, k1, qf[ds]);
      }
      const int qg = qrow0 + l31;
      const bool domask = (kt * 64 + 63) > qrow0;
      float pv0[16], pv1[16];
      float pmax = -1e30f;
      #pragma unroll
      for (int r = 0; r < 16; ++r){
        const int krow = (r & 3) + 8 * (r >> 2) + 4 * hi;
        float v0 = s0[r] * 0.08838834764831845f;
        float v1 = s1[r] * 0.08838834764831845f;
        if (domask){
          if (kt * 64 + krow > qg)      v0 = -1e30f;
          if (kt * 64 + 32 + krow > qg) v1 = -1e30f;
        }
        pv0[r] = v0; pv1[r] = v1;
        pmax = fmaxf(pmax, fmaxf(v0, v1));
      }
      pmax = fmaxf(pmax, __shfl_xor(pmax, 32));
      if (!__all(pmax - mx <= 8.f)){
        const float mn = fmaxf(mx, pmax);
        const float al = __expf(mx - mn);
        mx = mn; lsum *= al;
        #pragma unroll
        for (int r = 0; r < 16; ++r){
          const float ar = __shfl(al, (r & 3) + 8 * (r >> 2) + 4 * hi);
          acc[0][r] *= ar; acc[1][r] *= ar; acc[2][r] *= ar; acc[3][r] *= ar;
        }
      }
      float rs = 0.f;
      #pragma unroll
      for (int r = 0; r < 16; ++r){
        const float e0 = __expf(pv0[r] - mx);
        const float e1 = __expf(pv1[r] - mx);
        pv0[r] = e0; pv1[r] = e1;
        rs += e0 + e1;
      }
      rs += __shfl_xor(rs, 32);
      lsum += rs;
      #pragma unroll
      for (int s = 0; s < 4; ++s){
        const int t8 = (s & 1) * 8;
        unsigned w0, w1, w2, w3;
        if (s < 2){
          asm("v_cvt_pk_bf16_f32 %0, %1, %2" : "=v"(w0) : "v"(pv0[t8+0]), "v"(pv0[t8+1]));
          asm("v_cvt_pk_bf16_f32 %0, %1, %2" : "=v"(w1) : "v"(pv0[t8+2]), "v"(pv0[t8+3]));
          asm("v_cvt_pk_bf16_f32 %0, %1, %2" : "=v"(w2) : "v"(pv0[t8+4]), "v"(pv0[t8+5]));
          asm("v_cvt_pk_bf16_f32 %0, %1, %2" : "=v"(w3) : "v"(pv0[t8+6]), "v"(pv0[t8+7]));
        } else {
          asm("v_cvt_pk_bf16_f32 %0, %1, %2" : "=v"(w0) : "v"(pv1[t8+0]), "v"(pv1[t8+1]));
          asm("v_cvt_pk_bf16_f32 %0, %1, %2" : "=v"(w1) : "v"(pv1[t8+2]), "v"(pv1[t8+3]));
          asm("v_cvt_pk_bf16_f32 %0, %1, %2" : "=v"(w2) : "v"(pv1[t8+4]), "v"(pv1[t8+5]));
          asm("v_cvt_pk_bf16_f32 %0, %1, %2" : "=v"(w3) : "v"(pv1[t8+6]), "v"(pv1[t8+7]));
        }
        asm("v_permlane32_swap_b32 %0, %1" : "+v"(w0), "+v"(w2));
        asm("v_permlane32_swap_b32 %0, %1" : "+v"(w1), "+v"(w3));
        u32x4 pw = {w0, w1, w2, w3};
        s16x8 pa = __builtin_bit_cast(s16x8, pw);
        #pragma unroll
        for (int db = 0; db < 4; ++db){
          const int d = db * 32 + l31;
          s16x8 vf = *(const s16x8*)(sVc + d * 128 + (((s * 2 + hi) ^ (d & 7)) << 4));
          MFMA32(acc[db], pa, vf);
        }
      }
    }
    asm volatile("s_waitcnt lgkmcnt(0)");
    __builtin_amdgcn_s_barrier();
  }
  float li[16];
  #pragma unroll
  for (int r = 0; r < 16; ++r)
    li[r] = __shfl(lsum, (r & 3) + 8 * (r >> 2) + 4 * hi);
  #pragma unroll
  for (int db = 0; db < 4; ++db)
    #pragma unroll
    for (int r = 0; r < 16; ++r){
      const int row = qrow0 + (r & 3) + 8 * (r >> 2) + 4 * hi;
      const int col = h * 128 + db * 32 + l31;
      ob[((size_t)(b * 2048) + row) * 2048 + col] = f2b(acc[db][r] / li[r]);
    }
}

extern "C" void kernel_launch(void* const* d_in, const int* in_sizes, int n_in,
                              void* d_out, int out_size, void* d_ws, size_t ws_size,
                              hipStream_t stream){
  const float* hs   = (const float*)d_in[0];
  const float* cosT = (const float*)d_in[1];
  const float* sinT = (const float*)d_in[2];
  const float* Wq = (const float*)d_in[4];
  const float* Wk = (const float*)d_in[5];
  const float* Wv = (const float*)d_in[6];
  const float* Wo = (const float*)d_in[7];
  const float* qw = (const float*)d_in[8];
  const float* kw = (const float*)d_in[9];
  float* out = (float*)d_out;
  char* ws = (char*)d_ws;

  // workspace layout (88 MB)
  u16* hsb   = (u16*)(ws);                       // 16 MB  hs bf16
  u16* wqkvT = (u16*)(ws + ((size_t)16 << 20));  // 16 MB
  u16* woT   = (u16*)(ws + ((size_t)32 << 20));  //  8 MB
  u16* qb    = (u16*)(ws + ((size_t)40 << 20));  // 16 MB
  u16* kb2   = (u16*)(ws + ((size_t)56 << 20));  //  8 MB
  u16* vtb   = (u16*)(ws + ((size_t)64 << 20));  //  8 MB (transposed [bh][d][s])
  u16* attnb = (u16*)(ws + ((size_t)72 << 20));  // 16 MB

  k_cast<<<4096, 256, 0, stream>>>(hs, hsb, 1048576);
  k_transall<<<dim3(64, 256), 256, 0, stream>>>(Wq, Wk, Wv, Wo, wqkvT, woT);
  k_gemm8<4, 1><<<dim3(16, 16), 512, 0, stream>>>(hsb, wqkvT, nullptr, 4096, 4096, 2048,
                                                  qb, kb2, vtb, cosT, sinT, qw, kw);
  k_attn<<<512, 256, 0, stream>>>(qb, kb2, vtb, attnb);
  k_gemm8<2, 0><<<dim3(16, 16), 512, 0, stream>>>(attnb, woT, (float*)out, 4096, 2048, 2048,
                                                  nullptr, nullptr, nullptr, nullptr, nullptr, nullptr, nullptr);
}